// Round 1
// baseline (370.018 us; speedup 1.0000x reference)
//
#include <hip/hip_runtime.h>
#include <math.h>

#define WID 512
#define NB  32
#define NC  3

// Reference constants (computed to match numpy/jax float64 -> float32 folding)
constexpr float SCALE_F   = (float)(4.0 / 511.0);               // ID_OFFSET/(W-1)
constexpr float DEF_OFF_F = (float)((2.0 + 4.0 / 511.0) * 0.5); // (2+SCALE)/2
constexpr float CLIP_F    = 0.03125f;                            // PIX_W*EPS = (2/512)*8

__device__ __forceinline__ int refl(int r) {
  r = r < 0 ? -r : r;
  return r > WID - 1 ? 2 * (WID - 1) - r : r;
}

__device__ __forceinline__ float seqf(int i) {
  // IDEN coordinate: (2i - 511)/511
  return ((float)(2 * i - 511)) / 511.0f;
}

// ---------------- x-channel: blur + diff/relu + row cumsum ----------------
// one block per (b, row i); 512 threads = one per column
__global__ __launch_bounds__(512)
void kx_kernel(const float* __restrict__ pg, float* __restrict__ gridx,
               float kw0, float kw1, float kw2) {
  const int i = blockIdx.x & (WID - 1);
  const int b = blockIdx.x >> 9;
  const int j = threadIdx.x;
  const float* base = pg + (size_t)b * 2 * WID * WID; // channel 0

  const float* r0 = base + (size_t)refl(i - 2) * WID;
  const float* r1 = base + (size_t)refl(i - 1) * WID;
  const float* r2 = base + (size_t)i * WID;
  const float* r3 = base + (size_t)refl(i + 1) * WID;
  const float* r4 = base + (size_t)refl(i + 2) * WID;
  // vertical blur
  float v = kw2 * r2[j] + kw1 * (r1[j] + r3[j]) + kw0 * (r0[j] + r4[j]);

  __shared__ float hb[WID + 4];
  hb[j + 2] = v;
  if (j == 1)       hb[1]       = v; // col -1 -> 1
  if (j == 2)       hb[0]       = v; // col -2 -> 2
  if (j == WID - 2) hb[WID + 2] = v; // col W  -> W-2
  if (j == WID - 3) hb[WID + 3] = v; // col W+1-> W-3
  __syncthreads();
  // horizontal blur
  float h = kw2 * hb[j + 2] + kw1 * (hb[j + 1] + hb[j + 3]) + kw0 * (hb[j] + hb[j + 4]);

  float gx = seqf(j);
  float s  = h + gx + DEF_OFF_F;

  __shared__ float sb[WID];
  sb[j] = s;
  __syncthreads();
  float sprev = (j == 0) ? 0.0f : sb[j - 1];
  float a = fmaxf((s - sprev) / SCALE_F, 0.0f) * SCALE_F;

  // block-wide inclusive scan (wave64 shuffle scan + LDS wave combine)
  const int lane = j & 63, wv = j >> 6;
  float x = a;
#pragma unroll
  for (int off = 1; off < 64; off <<= 1) {
    float n = __shfl_up(x, off, 64);
    if (lane >= off) x += n;
  }
  __shared__ float wsum[8];
  __shared__ float woff[8];
  if (lane == 63) wsum[wv] = x;
  __syncthreads();
  if (threadIdx.x == 0) {
    float run = 0.0f;
#pragma unroll
    for (int w = 0; w < 8; ++w) { woff[w] = run; run += wsum[w]; }
  }
  __syncthreads();
  float cum = x + woff[wv];

  float d = cum - DEF_OFF_F - gx;
  d = fminf(fmaxf(d, -CLIP_F), CLIP_F);
  float g = fminf(fmaxf(d + gx, -1.0f), 1.0f);
  gridx[((size_t)b * WID + i) * WID + j] = g;
}

// ---------------- y-channel: blur + diff/relu + column cumsum ----------------
// one block per (b, 64-col tile); 8 waves, each owns a 64-row segment.
// pass A: per-segment sums of a; LDS exchange; pass B: recompute + emit cumsum.
#define KY_COLS 64
#define KY_SEGS 8
#define KY_ROWS (WID / KY_SEGS)

__global__ __launch_bounds__(512)
void ky_kernel(const float* __restrict__ pg, float* __restrict__ gridy,
               float kw0, float kw1, float kw2) {
  const int tile = blockIdx.x & 7;
  const int b    = blockIdx.x >> 3;
  const int lane = threadIdx.x & 63;
  const int wv   = threadIdx.x >> 6; // segment
  const int j    = tile * KY_COLS + lane;
  const float* base = pg + ((size_t)b * 2 + 1) * WID * WID; // channel 1

  const int jm2 = refl(j - 2), jm1 = refl(j - 1), jp1 = refl(j + 1), jp2 = refl(j + 2);

  auto hrow = [&](int r) -> float {
    const float* rp = base + (size_t)r * WID;
    return kw2 * rp[j] + kw1 * (rp[jm1] + rp[jp1]) + kw0 * (rp[jm2] + rp[jp2]);
  };

  const int r0 = wv * KY_ROWS;
  const int istart = (r0 == 0) ? 0 : r0 - 1;
  const int iend = r0 + KY_ROWS;

  __shared__ float segsum[KY_SEGS][KY_COLS];

  // ---- pass A: segment sum of a ----
  {
    float hm2 = hrow(refl(istart - 2));
    float hm1 = hrow(refl(istart - 1));
    float hc  = hrow(istart);
    float hp1 = hrow(refl(istart + 1));
    float hp2 = hrow(refl(istart + 2));
    float sprev = 0.0f;
    float suma  = 0.0f;
    for (int i = istart; i < iend; ++i) {
      float blur = kw2 * hc + kw1 * (hm1 + hp1) + kw0 * (hm2 + hp2);
      float s = blur + seqf(i) + DEF_OFF_F;
      if (i >= r0) {
        float a = fmaxf((s - sprev) / SCALE_F, 0.0f) * SCALE_F;
        suma += a;
      }
      sprev = s;
      hm2 = hm1; hm1 = hc; hc = hp1; hp1 = hp2;
      hp2 = hrow(refl(i + 3));
    }
    segsum[wv][lane] = suma;
  }
  __syncthreads();

  float off = 0.0f;
#pragma unroll
  for (int w = 0; w < KY_SEGS; ++w)
    if (w < wv) off += segsum[w][lane];

  // ---- pass B: recompute, add offset, clip, write ----
  {
    float hm2 = hrow(refl(istart - 2));
    float hm1 = hrow(refl(istart - 1));
    float hc  = hrow(istart);
    float hp1 = hrow(refl(istart + 1));
    float hp2 = hrow(refl(istart + 2));
    float sprev = 0.0f;
    float cum   = off;
    float* ob = gridy + (size_t)b * WID * WID;
    for (int i = istart; i < iend; ++i) {
      float blur = kw2 * hc + kw1 * (hm1 + hp1) + kw0 * (hm2 + hp2);
      float gy = seqf(i);
      float s = blur + gy + DEF_OFF_F;
      if (i >= r0) {
        float a = fmaxf((s - sprev) / SCALE_F, 0.0f) * SCALE_F;
        cum += a;
        float d = cum - DEF_OFF_F - gy;
        d = fminf(fmaxf(d, -CLIP_F), CLIP_F);
        float g = fminf(fmaxf(d + gy, -1.0f), 1.0f);
        ob[(size_t)i * WID + j] = g;
      }
      sprev = s;
      hm2 = hm1; hm1 = hc; hc = hp1; hp1 = hp2;
      hp2 = hrow(refl(i + 3));
    }
  }
}

// ---------------- bilinear grid sample ----------------
__global__ __launch_bounds__(256)
void sample_kernel(const float* __restrict__ img, const float* __restrict__ gridx,
                   const float* __restrict__ gridy, float* __restrict__ out) {
  size_t t = (size_t)blockIdx.x * 256 + threadIdx.x; // over B*W*W
  const int j = (int)(t & (WID - 1));
  const int i = (int)((t >> 9) & (WID - 1));
  const int b = (int)(t >> 18);
  (void)j; (void)i;

  float gx = gridx[t];
  float gy = gridy[t];
  float x = (gx + 1.0f) * 0.5f * (float)(WID - 1);
  float y = (gy + 1.0f) * 0.5f * (float)(WID - 1);
  float x0f = floorf(x), y0f = floorf(y);
  int x0 = (int)x0f, y0 = (int)y0f;
  float wx1 = x - x0f, wx0 = 1.0f - wx1;
  float wy1 = y - y0f, wy0 = 1.0f - wy1;
  int x1 = x0 + 1, y1 = y0 + 1;
  int x1c = x1 > WID - 1 ? WID - 1 : x1;
  int y1c = y1 > WID - 1 ? WID - 1 : y1;
  float vx1 = x1 < WID ? 1.0f : 0.0f; // weight is 0 there anyway; keep exact ref semantics
  float vy1 = y1 < WID ? 1.0f : 0.0f;

  float w00 = wx0 * wy0;
  float w01 = wx1 * wy0 * vx1;
  float w10 = wx0 * wy1 * vy1;
  float w11 = wx1 * wy1 * vx1 * vy1;

  size_t p00 = (size_t)y0  * WID + x0;
  size_t p01 = (size_t)y0  * WID + x1c;
  size_t p10 = (size_t)y1c * WID + x0;
  size_t p11 = (size_t)y1c * WID + x1c;

  const float* ib = img + (size_t)b * NC * WID * WID;
  float* ob = out + (size_t)b * NC * WID * WID;
  size_t pix = t & ((size_t)WID * WID - 1);
#pragma unroll
  for (int c = 0; c < NC; ++c) {
    const float* ic = ib + (size_t)c * WID * WID;
    float r = w00 * ic[p00] + w01 * ic[p01] + w10 * ic[p10] + w11 * ic[p11];
    ob[(size_t)c * WID * WID + pix] = r;
  }
}

extern "C" void kernel_launch(void* const* d_in, const int* in_sizes, int n_in,
                              void* d_out, int out_size, void* d_ws, size_t ws_size,
                              hipStream_t stream) {
  const float* img = (const float*)d_in[0]; // (B,C,W,W)
  const float* pg  = (const float*)d_in[1]; // (B,2,W,W)
  float* out = (float*)d_out;               // (B,C,W,W)

  // ws layout: gridx[B*W*W] fp32, gridy[B*W*W] fp32  (needs 64 MiB)
  float* gridx = (float*)d_ws;
  float* gridy = gridx + (size_t)NB * WID * WID;

  // Gaussian weights (match numpy float64 computation, then cast to float)
  double sigma = 5.0 * 0.15 + 0.35;
  double p0 = exp(-0.5 * (2.0 / sigma) * (2.0 / sigma));
  double p1 = exp(-0.5 * (1.0 / sigma) * (1.0 / sigma));
  double p2 = 1.0;
  double sum = 2.0 * p0 + 2.0 * p1 + p2;
  float kw0 = (float)(p0 / sum), kw1 = (float)(p1 / sum), kw2 = (float)(p2 / sum);

  kx_kernel<<<NB * WID, 512, 0, stream>>>(pg, gridx, kw0, kw1, kw2);
  ky_kernel<<<NB * 8, 512, 0, stream>>>(pg, gridy, kw0, kw1, kw2);
  sample_kernel<<<(NB * WID * WID) / 256, 256, 0, stream>>>(img, gridx, gridy, out);
}

// Round 2
// 361.491 us; speedup vs baseline: 1.0236x; 1.0236x over previous
//
#include <hip/hip_runtime.h>
#include <math.h>

#define WID 512
#define NB  32
#define NC  3
#define WW  (WID * WID)

constexpr float SCALE_F   = (float)(4.0 / 511.0);
constexpr float DEF_OFF_F = (float)((2.0 + 4.0 / 511.0) * 0.5);
constexpr float CLIP_F    = 0.03125f; // PIX_W*EPS

__device__ __forceinline__ int refl(int r) {
  r = r < 0 ? -r : r;
  return r > WID - 1 ? 2 * (WID - 1) - r : r;
}

__device__ __forceinline__ float seqf(int i) {
  return ((float)(2 * i - 511)) / 511.0f;
}

// ---------------- x-channel: wave-per-row, no LDS, no barriers ----------------
// block = 512 threads = 8 waves; wave handles one (b,row); lane holds 8 cols.
__global__ __launch_bounds__(512)
void kx_kernel(const float* __restrict__ pg, float* __restrict__ gridx,
               float kw0, float kw1, float kw2) {
  const int lane = threadIdx.x & 63;
  const int wv   = threadIdx.x >> 6;
  const int R = blockIdx.x * 8 + wv;        // global row id over B*W
  const int b = R >> 9;
  const int i = R & (WID - 1);
  const float* base = pg + (size_t)b * 2 * WW; // channel 0

  // vertical blur into v[8] (cols lane*8 .. lane*8+7)
  float v[8] = {0.f,0.f,0.f,0.f,0.f,0.f,0.f,0.f};
  const int rows[5] = {refl(i - 2), refl(i - 1), i, refl(i + 1), refl(i + 2)};
  const float wts[5] = {kw0, kw1, kw2, kw1, kw0};
#pragma unroll
  for (int r = 0; r < 5; ++r) {
    const float4* p = (const float4*)(base + (size_t)rows[r] * WID + lane * 8);
    float4 A = p[0], Bq = p[1];
    float w = wts[r];
    v[0] += w * A.x;  v[1] += w * A.y;  v[2] += w * A.z;  v[3] += w * A.w;
    v[4] += w * Bq.x; v[5] += w * Bq.y; v[6] += w * Bq.z; v[7] += w * Bq.w;
  }

  // horizontal blur: neighbors via shuffle, reflect at row ends
  float em1 = __shfl_up(v[7], 1, 64);   // col 8L-1
  float em2 = __shfl_up(v[6], 1, 64);   // col 8L-2
  float ep8 = __shfl_down(v[0], 1, 64); // col 8L+8
  float ep9 = __shfl_down(v[1], 1, 64); // col 8L+9
  if (lane == 0)  { em1 = v[1]; em2 = v[2]; }   // col -1->1, -2->2
  if (lane == 63) { ep8 = v[6]; ep9 = v[5]; }   // col 512->510, 513->509

  float h[8];
  h[0] = kw2 * v[0] + kw1 * (em1 + v[1]) + kw0 * (em2 + v[2]);
  h[1] = kw2 * v[1] + kw1 * (v[0] + v[2]) + kw0 * (em1 + v[3]);
#pragma unroll
  for (int k = 2; k < 6; ++k)
    h[k] = kw2 * v[k] + kw1 * (v[k - 1] + v[k + 1]) + kw0 * (v[k - 2] + v[k + 2]);
  h[6] = kw2 * v[6] + kw1 * (v[5] + v[7]) + kw0 * (v[4] + ep8);
  h[7] = kw2 * v[7] + kw1 * (v[6] + ep8) + kw0 * (v[5] + ep9);

  float s[8], a[8], p[8];
#pragma unroll
  for (int k = 0; k < 8; ++k) s[k] = h[k] + seqf(lane * 8 + k) + DEF_OFF_F;

  float sm1 = __shfl_up(s[7], 1, 64);
  if (lane == 0) sm1 = 0.0f;
  a[0] = fmaxf((s[0] - sm1) / SCALE_F, 0.0f) * SCALE_F;
#pragma unroll
  for (int k = 1; k < 8; ++k)
    a[k] = fmaxf((s[k] - s[k - 1]) / SCALE_F, 0.0f) * SCALE_F;

  // in-lane inclusive prefix
  p[0] = a[0];
#pragma unroll
  for (int k = 1; k < 8; ++k) p[k] = p[k - 1] + a[k];
  // wave scan of per-lane totals
  float incl = p[7];
#pragma unroll
  for (int off = 1; off < 64; off <<= 1) {
    float n = __shfl_up(incl, off, 64);
    if (lane >= off) incl += n;
  }
  float excl = incl - p[7];

  float og[8];
#pragma unroll
  for (int k = 0; k < 8; ++k) {
    float gx = seqf(lane * 8 + k);
    float d = (p[k] + excl) - DEF_OFF_F - gx;
    d = fminf(fmaxf(d, -CLIP_F), CLIP_F);
    og[k] = fminf(fmaxf(d + gx, -1.0f), 1.0f);
  }
  float4* o = (float4*)(gridx + ((size_t)b * WID + i) * WID + lane * 8);
  o[0] = make_float4(og[0], og[1], og[2], og[3]);
  o[1] = make_float4(og[4], og[5], og[6], og[7]);
}

// ---------------- y-channel: half-wave per 32-row segment, register a-cache ----
// block = 512 threads = 16 half-waves; tile = 32 cols; segment = 32 rows.
__global__ __launch_bounds__(512)
void ky_kernel(const float* __restrict__ pg, float* __restrict__ gridy,
               float kw0, float kw1, float kw2) {
  const int tile = blockIdx.x & 15;
  const int b    = blockIdx.x >> 4;
  const int half = threadIdx.x >> 5;   // 0..15 = row segment
  const int l32  = threadIdx.x & 31;
  const int j    = tile * 32 + l32;
  const float* base = pg + ((size_t)b * 2 + 1) * WW; // channel 1

  const int jm1 = refl(j - 1), jm2 = refl(j - 2);
  const int jp1 = refl(j + 1), jp2 = refl(j + 2);

  auto hrow = [&](int r) -> float {
    const float* rp = base + (size_t)r * WID;
    float val = rp[j];
    float vm1 = __shfl_up(val, 1, 32);
    float vm2 = __shfl_up(val, 2, 32);
    float vp1 = __shfl_down(val, 1, 32);
    float vp2 = __shfl_down(val, 2, 32);
    if (l32 == 0)  vm1 = rp[jm1];
    if (l32 < 2)   vm2 = rp[jm2];
    if (l32 == 31) vp1 = rp[jp1];
    if (l32 >= 30) vp2 = rp[jp2];
    return kw2 * val + kw1 * (vm1 + vp1) + kw0 * (vm2 + vp2);
  };

  const int r0 = half * 32;
  const int istart = r0 - 1;           // uniform for all halves (half 0: -1)

  float hm2 = hrow(refl(istart - 2));
  float hm1 = hrow(refl(istart - 1));
  float hc  = hrow(refl(istart));
  float hp1 = hrow(refl(istart + 1));
  float hp2 = hrow(refl(istart + 2));

  float areg[32];
  float sprev = 0.0f, suma = 0.0f;
#pragma unroll
  for (int k = 0; k <= 32; ++k) {
    const int i = istart + k;
    float blur = kw2 * hc + kw1 * (hm1 + hp1) + kw0 * (hm2 + hp2);
    float s = blur + seqf(i) + DEF_OFF_F;
    if (k == 0) {
      sprev = (half == 0) ? 0.0f : s;
    } else {
      float a = fmaxf((s - sprev) / SCALE_F, 0.0f) * SCALE_F;
      areg[k - 1] = a;
      suma += a;
      sprev = s;
    }
    if (k < 32) {
      hm2 = hm1; hm1 = hc; hc = hp1; hp1 = hp2;
      hp2 = hrow(refl(i + 3));
    }
  }

  __shared__ float segsum[16][32];
  segsum[half][l32] = suma;
  __syncthreads();

  float off = 0.0f;
#pragma unroll
  for (int w = 0; w < 16; ++w)
    if (w < half) off += segsum[w][l32];

  float* ob = gridy + (size_t)b * WW;
  float cum = off;
#pragma unroll
  for (int k = 0; k < 32; ++k) {
    const int i = r0 + k;
    cum += areg[k];
    float gy = seqf(i);
    float d = cum - DEF_OFF_F - gy;
    d = fminf(fmaxf(d, -CLIP_F), CLIP_F);
    ob[(size_t)i * WID + j] = fminf(fmaxf(d + gy, -1.0f), 1.0f);
  }
}

// ---------------- bilinear sample: 4 px/thread, XCD-contiguous swizzle -------
#define SAMP_BLOCKS (NB * WW / 1024)   // 8192
__global__ __launch_bounds__(256)
void sample_kernel(const float* __restrict__ img, const float* __restrict__ gridx,
                   const float* __restrict__ gridy, float* __restrict__ out) {
  // remap so each XCD (blockIdx%8) gets a contiguous pixel chunk
  const int nb = (blockIdx.x & 7) * (SAMP_BLOCKS / 8) + (blockIdx.x >> 3);
  const size_t t0 = ((size_t)nb * 256 + threadIdx.x) * 4;
  const int b   = (int)(t0 >> 18);
  const int pix = (int)(t0 & (WW - 1));

  const float4 gx4 = *(const float4*)(gridx + t0);
  const float4 gy4 = *(const float4*)(gridy + t0);
  const float gxa[4] = {gx4.x, gx4.y, gx4.z, gx4.w};
  const float gya[4] = {gy4.x, gy4.y, gy4.z, gy4.w};

  int o00[4], o01[4], o10[4], o11[4];
  float w00[4], w01[4], w10[4], w11[4];
#pragma unroll
  for (int p = 0; p < 4; ++p) {
    float x = (gxa[p] + 1.0f) * 0.5f * (float)(WID - 1);
    float y = (gya[p] + 1.0f) * 0.5f * (float)(WID - 1);
    float x0f = floorf(x), y0f = floorf(y);
    int x0 = (int)x0f, y0 = (int)y0f;
    float wx1 = x - x0f, wx0 = 1.0f - wx1;
    float wy1 = y - y0f, wy0 = 1.0f - wy1;
    int x1 = x0 + 1, y1 = y0 + 1;
    int x1c = x1 > WID - 1 ? WID - 1 : x1;
    int y1c = y1 > WID - 1 ? WID - 1 : y1;
    float vx1 = x1 < WID ? 1.0f : 0.0f;
    float vy1 = y1 < WID ? 1.0f : 0.0f;
    w00[p] = wx0 * wy0;
    w01[p] = wx1 * wy0 * vx1;
    w10[p] = wx0 * wy1 * vy1;
    w11[p] = wx1 * wy1 * vx1 * vy1;
    o00[p] = y0 * WID + x0;
    o01[p] = y0 * WID + x1c;
    o10[p] = y1c * WID + x0;
    o11[p] = y1c * WID + x1c;
  }

  const float* ib = img + (size_t)b * NC * WW;
  float* ob = out + (size_t)b * NC * WW + pix;
#pragma unroll
  for (int c = 0; c < NC; ++c) {
    const float* ic = ib + (size_t)c * WW;
    float r[4];
#pragma unroll
    for (int p = 0; p < 4; ++p)
      r[p] = w00[p] * ic[o00[p]] + w01[p] * ic[o01[p]] +
             w10[p] * ic[o10[p]] + w11[p] * ic[o11[p]];
    *(float4*)(ob + (size_t)c * WW) = make_float4(r[0], r[1], r[2], r[3]);
  }
}

extern "C" void kernel_launch(void* const* d_in, const int* in_sizes, int n_in,
                              void* d_out, int out_size, void* d_ws, size_t ws_size,
                              hipStream_t stream) {
  const float* img = (const float*)d_in[0];
  const float* pg  = (const float*)d_in[1];
  float* out = (float*)d_out;

  float* gridx = (float*)d_ws;
  float* gridy = gridx + (size_t)NB * WW;

  double sigma = 5.0 * 0.15 + 0.35;
  double p0 = exp(-0.5 * (2.0 / sigma) * (2.0 / sigma));
  double p1 = exp(-0.5 * (1.0 / sigma) * (1.0 / sigma));
  double p2 = 1.0;
  double sum = 2.0 * p0 + 2.0 * p1 + p2;
  float kw0 = (float)(p0 / sum), kw1 = (float)(p1 / sum), kw2 = (float)(p2 / sum);

  kx_kernel<<<NB * WID / 8, 512, 0, stream>>>(pg, gridx, kw0, kw1, kw2);
  ky_kernel<<<NB * 16, 512, 0, stream>>>(pg, gridy, kw0, kw1, kw2);
  sample_kernel<<<SAMP_BLOCKS, 256, 0, stream>>>(img, gridx, gridy, out);
}

// Round 3
// 335.898 us; speedup vs baseline: 1.1016x; 1.0762x over previous
//
#include <hip/hip_runtime.h>
#include <math.h>

#define WID 512
#define NB  32
#define NC  3
#define WW  (WID * WID)

constexpr float SCALE_F   = (float)(4.0 / 511.0);
constexpr float DEF_OFF_F = (float)((2.0 + 4.0 / 511.0) * 0.5);
constexpr float CLIP_F    = 0.03125f; // PIX_W*EPS -> max displacement 7.984 px

__device__ __forceinline__ int refl(int r) {
  r = r < 0 ? -r : r;
  return r > WID - 1 ? 2 * (WID - 1) - r : r;
}

__device__ __forceinline__ float seqf(int i) {
  return ((float)(2 * i - 511)) / 511.0f;
}

// ---------------- x-channel: wave-per-row, no LDS, no barriers ----------------
__global__ __launch_bounds__(512)
void kx_kernel(const float* __restrict__ pg, float* __restrict__ gridx,
               float kw0, float kw1, float kw2) {
  const int lane = threadIdx.x & 63;
  const int wv   = threadIdx.x >> 6;
  const int R = blockIdx.x * 8 + wv;
  const int b = R >> 9;
  const int i = R & (WID - 1);
  const float* base = pg + (size_t)b * 2 * WW;

  float v[8] = {0.f,0.f,0.f,0.f,0.f,0.f,0.f,0.f};
  const int rows[5] = {refl(i - 2), refl(i - 1), i, refl(i + 1), refl(i + 2)};
  const float wts[5] = {kw0, kw1, kw2, kw1, kw0};
#pragma unroll
  for (int r = 0; r < 5; ++r) {
    const float4* p = (const float4*)(base + (size_t)rows[r] * WID + lane * 8);
    float4 A = p[0], Bq = p[1];
    float w = wts[r];
    v[0] += w * A.x;  v[1] += w * A.y;  v[2] += w * A.z;  v[3] += w * A.w;
    v[4] += w * Bq.x; v[5] += w * Bq.y; v[6] += w * Bq.z; v[7] += w * Bq.w;
  }

  float em1 = __shfl_up(v[7], 1, 64);
  float em2 = __shfl_up(v[6], 1, 64);
  float ep8 = __shfl_down(v[0], 1, 64);
  float ep9 = __shfl_down(v[1], 1, 64);
  if (lane == 0)  { em1 = v[1]; em2 = v[2]; }
  if (lane == 63) { ep8 = v[6]; ep9 = v[5]; }

  float h[8];
  h[0] = kw2 * v[0] + kw1 * (em1 + v[1]) + kw0 * (em2 + v[2]);
  h[1] = kw2 * v[1] + kw1 * (v[0] + v[2]) + kw0 * (em1 + v[3]);
#pragma unroll
  for (int k = 2; k < 6; ++k)
    h[k] = kw2 * v[k] + kw1 * (v[k - 1] + v[k + 1]) + kw0 * (v[k - 2] + v[k + 2]);
  h[6] = kw2 * v[6] + kw1 * (v[5] + v[7]) + kw0 * (v[4] + ep8);
  h[7] = kw2 * v[7] + kw1 * (v[6] + ep8) + kw0 * (v[5] + ep9);

  float s[8], a[8], p[8];
#pragma unroll
  for (int k = 0; k < 8; ++k) s[k] = h[k] + seqf(lane * 8 + k) + DEF_OFF_F;

  float sm1 = __shfl_up(s[7], 1, 64);
  if (lane == 0) sm1 = 0.0f;
  a[0] = fmaxf((s[0] - sm1) / SCALE_F, 0.0f) * SCALE_F;
#pragma unroll
  for (int k = 1; k < 8; ++k)
    a[k] = fmaxf((s[k] - s[k - 1]) / SCALE_F, 0.0f) * SCALE_F;

  p[0] = a[0];
#pragma unroll
  for (int k = 1; k < 8; ++k) p[k] = p[k - 1] + a[k];
  float incl = p[7];
#pragma unroll
  for (int off = 1; off < 64; off <<= 1) {
    float n = __shfl_up(incl, off, 64);
    if (lane >= off) incl += n;
  }
  float excl = incl - p[7];

  float og[8];
#pragma unroll
  for (int k = 0; k < 8; ++k) {
    float gx = seqf(lane * 8 + k);
    float d = (p[k] + excl) - DEF_OFF_F - gx;
    d = fminf(fmaxf(d, -CLIP_F), CLIP_F);
    og[k] = fminf(fmaxf(d + gx, -1.0f), 1.0f);
  }
  float4* o = (float4*)(gridx + ((size_t)b * WID + i) * WID + lane * 8);
  o[0] = make_float4(og[0], og[1], og[2], og[3]);
  o[1] = make_float4(og[4], og[5], og[6], og[7]);
}

// ---------------- y-channel: 1024 thr, wave per 32-row x 64-col segment ------
__global__ __launch_bounds__(1024)
void ky_kernel(const float* __restrict__ pg, float* __restrict__ gridy,
               float kw0, float kw1, float kw2) {
  const int tile = blockIdx.x & 7;   // 8 col-tiles of 64
  const int b    = blockIdx.x >> 3;
  const int wv   = threadIdx.x >> 6; // 0..15 row segment
  const int lane = threadIdx.x & 63;
  const int j    = tile * 64 + lane;
  const float* base = pg + ((size_t)b * 2 + 1) * WW;

  const int jm1 = refl(j - 1), jm2 = refl(j - 2);
  const int jp1 = refl(j + 1), jp2 = refl(j + 2);

  auto hrow = [&](int r) -> float {
    const float* rp = base + (size_t)r * WID;
    float val = rp[j];
    float vm1 = __shfl_up(val, 1, 64);
    float vm2 = __shfl_up(val, 2, 64);
    float vp1 = __shfl_down(val, 1, 64);
    float vp2 = __shfl_down(val, 2, 64);
    if (lane == 0)  vm1 = rp[jm1];
    if (lane < 2)   vm2 = rp[jm2];
    if (lane == 63) vp1 = rp[jp1];
    if (lane >= 62) vp2 = rp[jp2];
    return kw2 * val + kw1 * (vm1 + vp1) + kw0 * (vm2 + vp2);
  };

  const int r0 = wv * 32;
  const int istart = r0 - 1;

  float hm2 = hrow(refl(istart - 2));
  float hm1 = hrow(refl(istart - 1));
  float hc  = hrow(refl(istart));
  float hp1 = hrow(refl(istart + 1));
  float hp2 = hrow(refl(istart + 2));

  float areg[32];
  float sprev = 0.0f, suma = 0.0f;
#pragma unroll
  for (int k = 0; k <= 32; ++k) {
    const int i = istart + k;
    float blur = kw2 * hc + kw1 * (hm1 + hp1) + kw0 * (hm2 + hp2);
    float s = blur + seqf(i) + DEF_OFF_F;
    if (k == 0) {
      sprev = (wv == 0) ? 0.0f : s;
    } else {
      float a = fmaxf((s - sprev) / SCALE_F, 0.0f) * SCALE_F;
      areg[k - 1] = a;
      suma += a;
      sprev = s;
    }
    if (k < 32) {
      hm2 = hm1; hm1 = hc; hc = hp1; hp1 = hp2;
      hp2 = hrow(refl(i + 3));
    }
  }

  __shared__ float segsum[16][64];
  segsum[wv][lane] = suma;
  __syncthreads();

  float off = 0.0f;
#pragma unroll
  for (int w = 0; w < 16; ++w)
    if (w < wv) off += segsum[w][lane];

  float* ob = gridy + (size_t)b * WW;
  float cum = off;
#pragma unroll
  for (int k = 0; k < 32; ++k) {
    const int i = r0 + k;
    cum += areg[k];
    float gy = seqf(i);
    float d = cum - DEF_OFF_F - gy;
    d = fminf(fmaxf(d, -CLIP_F), CLIP_F);
    ob[(size_t)i * WID + j] = fminf(fmaxf(d + gy, -1.0f), 1.0f);
  }
}

// ---------------- LDS-staged bilinear sample --------------------------------
// Displacement <= 7.984 px  =>  rows needed for an 8-row tile: [r0-8, r0+15].
#define STILE  8
#define SROWS  24            // STILE + 8 up + 8 down
#define LSTR   516           // 512 + 4 pad (16B-aligned rows, de-phased banks)
#define SAMP_BLOCKS (NB * NC * (WID / STILE))  // 6144

__global__ __launch_bounds__(512)
void sample_kernel(const float* __restrict__ img, const float* __restrict__ gridx,
                   const float* __restrict__ gridy, float* __restrict__ out) {
  // swizzle: each XCD gets a contiguous chunk so adjacent tiles share halo in L2
  const int nb = (blockIdx.x & 7) * (SAMP_BLOCKS / 8) + (blockIdx.x >> 3);
  const int rt = nb & 63;            // 64 row-tiles
  const int bc = nb >> 6;            // b*3 + c
  const int b  = bc / 3;
  const int c  = bc - b * 3;
  const int r0 = rt * STILE;

  __shared__ float tile[SROWS * LSTR]; // 49.5 KB

  const float* ic = img + ((size_t)b * NC + c) * WW;
#pragma unroll
  for (int it = 0; it < (SROWS * 128) / 512; ++it) {
    int idx = it * 512 + threadIdx.x;
    int lr = idx >> 7;
    int c4 = (idx & 127) << 2;
    int gr = r0 - 8 + lr;
    gr = gr < 0 ? 0 : (gr > WID - 1 ? WID - 1 : gr);
    float4 vq = *(const float4*)(ic + (size_t)gr * WID + c4);
    *(float4*)(&tile[lr * LSTR + c4]) = vq;
  }
  __syncthreads();

  const int j = threadIdx.x;
  float* ob = out + ((size_t)b * NC + c) * WW;
#pragma unroll
  for (int r = 0; r < STILE; ++r) {
    const int i = r0 + r;
    const size_t gidx = ((size_t)b * WID + i) * WID + j;
    float gx = gridx[gidx];
    float gy = gridy[gidx];
    float x = (gx + 1.0f) * 0.5f * (float)(WID - 1);
    float y = (gy + 1.0f) * 0.5f * (float)(WID - 1);
    float x0f = floorf(x), y0f = floorf(y);
    int x0 = (int)x0f, y0 = (int)y0f;
    float wx1 = x - x0f, wx0 = 1.0f - wx1;
    float wy1 = y - y0f, wy0 = 1.0f - wy1;
    int x1 = x0 + 1, y1 = y0 + 1;
    int x1c = x1 > WID - 1 ? WID - 1 : x1;
    int y1c = y1 > WID - 1 ? WID - 1 : y1;
    float vx1 = x1 < WID ? 1.0f : 0.0f;
    float vy1 = y1 < WID ? 1.0f : 0.0f;

    float w00 = wx0 * wy0;
    float w01 = wx1 * wy0 * vx1;
    float w10 = wx0 * wy1 * vy1;
    float w11 = wx1 * wy1 * vx1 * vy1;

    int ly0 = y0 - r0 + 8;
    int ly1 = y1c - r0 + 8;
    float v00 = tile[ly0 * LSTR + x0];
    float v01 = tile[ly0 * LSTR + x1c];
    float v10 = tile[ly1 * LSTR + x0];
    float v11 = tile[ly1 * LSTR + x1c];

    ob[(size_t)i * WID + j] = w00 * v00 + w01 * v01 + w10 * v10 + w11 * v11;
  }
}

extern "C" void kernel_launch(void* const* d_in, const int* in_sizes, int n_in,
                              void* d_out, int out_size, void* d_ws, size_t ws_size,
                              hipStream_t stream) {
  const float* img = (const float*)d_in[0];
  const float* pg  = (const float*)d_in[1];
  float* out = (float*)d_out;

  float* gridx = (float*)d_ws;
  float* gridy = gridx + (size_t)NB * WW;

  double sigma = 5.0 * 0.15 + 0.35;
  double p0 = exp(-0.5 * (2.0 / sigma) * (2.0 / sigma));
  double p1 = exp(-0.5 * (1.0 / sigma) * (1.0 / sigma));
  double p2 = 1.0;
  double sum = 2.0 * p0 + 2.0 * p1 + p2;
  float kw0 = (float)(p0 / sum), kw1 = (float)(p1 / sum), kw2 = (float)(p2 / sum);

  kx_kernel<<<NB * WID / 8, 512, 0, stream>>>(pg, gridx, kw0, kw1, kw2);
  ky_kernel<<<NB * 8, 1024, 0, stream>>>(pg, gridy, kw0, kw1, kw2);
  sample_kernel<<<SAMP_BLOCKS, 512, 0, stream>>>(img, gridx, gridy, out);
}